// Round 2
// 72.997 us; speedup vs baseline: 1.0104x; 1.0104x over previous
//
#include <hip/hip_runtime.h>

#define KS 5
#define BETA 15.0f
#define LOG2E 1.4426950408889634f
#define LN2 0.6931471805599453f
#define SHIFT 16.0f

// y = logsumexp_{25 taps}((w + x_pad)*BETA)/BETA, zero padding.
// Exp-domain: E = 2^(x*scale - 16) (pad x=0 -> E=2^-16 exactly),
// W_t = 2^(w_t*scale) held in SGPRs, y = (log2(sum W_t*E_t) + 16)*ln2/BETA.
// Thread = 4 cols x 4 rows strip; 5x8 E-window slides down in registers.
// All loads branch-free (clamped addr + cndmask zeroing) and software-
// pipelined one input row ahead so L2 latency hides under the FMA block.
// Block 256 = 32 colgroups x 8 strips -> 32 rows; grid = 256 planes x 4.

__global__ __launch_bounds__(256) void morph_soft_dilate(
    const float* __restrict__ x,
    const float* __restrict__ wy,
    float* __restrict__ out)
{
    const int tid   = threadIdx.x;
    const int plane = blockIdx.x >> 2;         // b*64 + c
    const int rb    = blockIdx.x & 3;
    const int c     = plane & 63;
    const float scale = BETA * LOG2E;

    // Wave-uniform dilated weights -> SGPRs (frees 25 VGPRs, no LDS/barrier).
    // NOTE: readfirstlane is int(int) — must BITCAST, not pass float (value-
    // converts and truncates otherwise; that was round-1's correctness bug).
    float W[25];
#pragma unroll
    for (int t = 0; t < 25; ++t) {
        const float wv = __builtin_amdgcn_exp2f(wy[c * 25 + t] * scale);
        W[t] = __int_as_float(__builtin_amdgcn_readfirstlane(__float_as_int(wv)));
    }

    const int tx = tid & 31;          // colgroup: cols 4tx..4tx+3
    const int ty = tid >> 5;          // strip 0..7
    const int wc = tx * 4;
    const int h0 = rb * 32 + ty * 4;  // first output row
    const float* xp = x + (size_t)plane * 16384;
    float* op = out + (size_t)plane * 16384;
    const bool lok = (tx > 0);
    const bool rok = (tx < 31);

    // Branch-free raw-row load: clamp row for addressing, nudge halo pointers
    // in-range via cndmask, zero invalid lanes with selects after the load.
    auto loadRaw = [&](int row, float* xv) {
        const int rc = row < 0 ? 0 : (row > 127 ? 127 : row);
        const float* rp = xp + rc * 128 + wc;
        const float2 a = *(const float2*)(rp - (lok ? 2 : 0));
        const float4 b = *(const float4*)rp;
        const float2 d = *(const float2*)(rp + (rok ? 4 : 2));
        const bool rv = (unsigned)row < 128u;
        const bool lv = lok && rv;
        const bool rv2 = rok && rv;
        xv[0] = lv ? a.x : 0.0f;
        xv[1] = lv ? a.y : 0.0f;
        xv[2] = rv ? b.x : 0.0f;
        xv[3] = rv ? b.y : 0.0f;
        xv[4] = rv ? b.z : 0.0f;
        xv[5] = rv ? b.w : 0.0f;
        xv[6] = rv2 ? d.x : 0.0f;
        xv[7] = rv2 ? d.y : 0.0f;
    };

    auto cvtE = [&](const float* xv, float* E) {
#pragma unroll
        for (int k = 0; k < 8; ++k)
            E[k] = __builtin_amdgcn_exp2f(fmaf(xv[k], scale, -SHIFT));
    };

    float win[5][8];  // E-values for cols wc-2..wc+5, 5 input rows
    float nxt[8];     // raw x of the next input row (in-flight loads)

    // Prologue: issue loads for rows h0-2..h0+2; convert the first four.
    {
        float r[4][8];
#pragma unroll
        for (int k = 0; k < 4; ++k) loadRaw(h0 - 2 + k, r[k]);
        loadRaw(h0 + 2, nxt);
#pragma unroll
        for (int k = 0; k < 4; ++k) cvtE(r[k], win[k]);
    }

    const float kk = LN2 / BETA;
#pragma unroll
    for (int s = 0; s < 4; ++s) {
        // Convert the row whose loads were issued last iteration...
        cvtE(nxt, win[(4 + s) % 5]);
        // ...then immediately issue next iteration's loads so their latency
        // hides under this strip's 100 FMAs + 4 logs + store.
        if (s < 3) loadRaw(h0 + 3 + s, nxt);

        float a0 = 0.0f, a1 = 0.0f, a2 = 0.0f, a3 = 0.0f;
#pragma unroll
        for (int i = 0; i < KS; ++i) {
            const float* e = win[(s + i) % 5];
#pragma unroll
            for (int j = 0; j < KS; ++j) {
                const float wv = W[i * KS + j];
                a0 = fmaf(wv, e[j + 0], a0);
                a1 = fmaf(wv, e[j + 1], a1);
                a2 = fmaf(wv, e[j + 2], a2);
                a3 = fmaf(wv, e[j + 3], a3);
            }
        }

        float4 o;
        o.x = (__builtin_amdgcn_logf(a0) + SHIFT) * kk;
        o.y = (__builtin_amdgcn_logf(a1) + SHIFT) * kk;
        o.z = (__builtin_amdgcn_logf(a2) + SHIFT) * kk;
        o.w = (__builtin_amdgcn_logf(a3) + SHIFT) * kk;
        *(float4*)(op + (h0 + s) * 128 + wc) = o;
    }
}

extern "C" void kernel_launch(void* const* d_in, const int* in_sizes, int n_in,
                              void* d_out, int out_size, void* d_ws, size_t ws_size,
                              hipStream_t stream) {
    const float* x  = (const float*)d_in[0];
    const float* wy = (const float*)d_in[1];
    float* out      = (float*)d_out;

    // 256 planes x 4 row-blocks of 32 rows
    morph_soft_dilate<<<256 * 4, 256, 0, stream>>>(x, wy, out);
}